// Round 1
// baseline (4010.501 us; speedup 1.0000x reference)
//
#include <hip/hip_runtime.h>
#include <hip/hip_bf16.h>
#include <stdint.h>

#define SEQ    16384
#define NKL    11
#define NSTEP  395   // 1 center + 2*16 (l=0) + 2*9*20 (tents+2 corrections) + 2 (l=10 box)

typedef __attribute__((ext_vector_type(8))) short short8;
typedef __attribute__((ext_vector_type(4))) float f32x4;

// ---------------- level (pyramid) layout: per (b,i) row ----------------
// B2_s (s=2..512): double-box, support u in [-(2s-2), SEQ-1]
// B1_w (w=2..512): box,        support u in [-(w-1),  SEQ-1]
// M_w  (w=2..512): 1st moment, support u in [-(w-1),  SEQ-1]
__host__ __device__ inline int lenB2(int l){ return SEQ + (2<<l) + 8; }
__host__ __device__ inline int lenB1(int l){ return SEQ + (1<<l) + 8; }
__host__ __device__ inline long offB2(int l){ long o=0; for(int k=1;k<l;k++) o+=lenB2(k); return o; }
__host__ __device__ inline long totB2(){ long o=0; for(int k=1;k<=9;k++) o+=lenB2(k); return o; }
__host__ __device__ inline long offB1(int l){ long o=totB2(); for(int k=1;k<l;k++) o+=lenB1(k); return o; }
__host__ __device__ inline long totB1(){ long o=0; for(int k=1;k<=9;k++) o+=lenB1(k); return o; }
__host__ __device__ inline long offM(int l){ return totB1() + offB1(l); }
__host__ __device__ inline long rowElems(){ long r = totB2() + 2*totB1(); return (r + 127) & ~127L; }

__device__ inline float multf(int l){ return (float)(pow(0.5, (double)l/4096.0)*0.9 + 0.1); }

__device__ inline float Kv(const float* kern, int l, int g, int o, int i, int p){
  return kern[ (((size_t)((l*2 + g)*32 + o))*32 + i)*16 + p ];
}

__device__ inline short f2b(float v){
  __hip_bfloat16 h = __float2bfloat16(v);
  return __builtin_bit_cast(short, h);
}

struct SInfo { int type, l, g, p; };
// type: 0 center, 1 l0-raw-x tap, 2 tent, 3 FL corr, 4 FR corr, 5 l10 box
__device__ inline SInfo decode(int st){
  SInfo r;
  if (st == 0){ r.type=0; r.l=0; r.g=0; r.p=0; return r; }
  if (st < 17){ r.type=1; r.l=0; r.g=1; r.p=st-1;  return r; }
  if (st < 33){ r.type=1; r.l=0; r.g=0; r.p=st-17; return r; }
  if (st < 213){ int t=st-33;  int l=1+t/20, k=t%20;
    if (k<18){ r.type=2; r.l=l; r.g=1; r.p=k-1; } else { r.type=(k==18)?3:4; r.l=l; r.g=1; r.p=0; }
    return r; }
  if (st < 393){ int t=st-213; int l=1+t/20, k=t%20;
    if (k<18){ r.type=2; r.l=l; r.g=0; r.p=k-1; } else { r.type=(k==18)?3:4; r.l=l; r.g=0; r.p=0; }
    return r; }
  r.type=5; r.l=10; r.g=(st==393)?1:0; r.p=0; return r;
}

// ---------------- norm kernel ----------------
__global__ __launch_bounds__(256) void norm_k(const float* __restrict__ kern,
                                              const float* __restrict__ cen,
                                              float* __restrict__ invn){
  int o = blockIdx.x >> 5, i = blockIdx.x & 31, tid = threadIdx.x;
  float mlt[NKL];
  for (int l = 0; l < NKL; l++) mlt[l] = multf(l);
  double acc = 0.0;
  for (int pos = tid; pos < 2*SEQ; pos += 256){
    int g = pos >> 14;
    int r = pos & (SEQ-1);
    int lr = (r >> 4) + 1;
    int l  = 31 - __clz(lr);
    int s  = 1 << l;
    int j  = r - 16*(s - 1);
    float c = (j + 0.5f)/(float)s - 0.5f;
    c = fminf(fmaxf(c, 0.f), 15.f);
    int i0 = (int)floorf(c);
    int i1 = (i0+1 < 15) ? i0+1 : 15;
    float w = c - (float)i0;
    float v = Kv(kern,l,g,o,i,i0)*(1.f-w) + Kv(kern,l,g,o,i,i1)*w;
    v *= mlt[l];
    acc += (double)v * v;
  }
  __shared__ double sred[256];
  sred[tid] = acc; __syncthreads();
  for (int ofs = 128; ofs > 0; ofs >>= 1){ if (tid < ofs) sred[tid] += sred[tid+ofs]; __syncthreads(); }
  if (tid == 0){
    float cc = cen[o*32 + i];
    double tot = sred[0] + (double)cc*cc;
    invn[o*32 + i] = (float)(1.0 / sqrt(tot));
  }
}

// ---------------- weights kernel: W[step][o][i] bf16 ----------------
__global__ __launch_bounds__(256) void wts_k(const float* __restrict__ kern,
                                             const float* __restrict__ cen,
                                             const float* __restrict__ invn,
                                             __hip_bfloat16* __restrict__ wts){
  int st = blockIdx.x; SInfo si = decode(st);
  float mlt[NKL];
  for (int l = 0; l < NKL; l++) mlt[l] = multf(l);
  for (int idx = threadIdx.x; idx < 1024; idx += 256){
    int o = idx >> 5, i = idx & 31;
    float in = invn[o*32 + i];
    float w = 0.f;
    if (si.type == 0)      w = cen[o*32 + i] * in;
    else if (si.type == 1) w = mlt[0] * Kv(kern,0,si.g,o,i,si.p) * in;
    else if (si.type == 2){
      int s = 1 << si.l;
      int pp = si.p < 0 ? 0 : (si.p > 15 ? 15 : si.p);
      w = mlt[si.l] * Kv(kern,si.l,si.g,o,i,pp) * in * (0.5f/(float)s);
    }
    else if (si.type == 3) w = -mlt[si.l] * Kv(kern,si.l,si.g,o,i,0)  * in;
    else if (si.type == 4) w = -mlt[si.l] * Kv(kern,si.l,si.g,o,i,15) * in;
    else                   w =  mlt[10]   * Kv(kern,10,si.g,o,i,0)    * in;
    wts[(size_t)st*1024 + idx] = __float2bfloat16(w);
  }
}

// ---------------- pyramid kernel: one block per (row, quarter) ----------------
#define PBUF 6144
__global__ __launch_bounds__(256) void pyr_k(const float* __restrict__ x,
                                             __hip_bfloat16* __restrict__ lv,
                                             int b0, long rowe){
  __shared__ float bufA[PBUF], bufB[PBUF];
  __shared__ float sp[256], sq[256];
  int tid = threadIdx.x;
  int row = blockIdx.x >> 2, q = blockIdx.x & 3;
  int bl = row >> 5, i = row & 31;
  int b = b0 + bl;
  const float* X = x + ((size_t)(b*32 + i) << 14);
  __hip_bfloat16* R = lv + (size_t)row * rowe;
  int S0 = q*4096 - 1024;

  // ---- B2 chain ----
  float* cur = bufA; float* nxt = bufB;
  for (int idx = tid; idx < PBUF; idx += 256){
    int u = S0 + idx; cur[idx] = (u >= 0 && u < SEQ) ? X[u] : 0.f;
  }
  __syncthreads();
  for (int l = 1; l <= 9; l++){
    int s = 1 << l, hs = s >> 1;
    int limit = PBUF - (2*s - 1);
    for (int idx = tid; idx < limit; idx += 256)
      nxt[idx] = cur[idx] + 2.f*cur[idx+hs] + cur[idx+s];
    __syncthreads();
    int ust = (q == 0) ? -(2*s - 2) : q*4096;
    int uen = q*4096 + 4096;
    long ob = offB2(l);
    for (int uu = ust + tid; uu < uen; uu += 256)
      R[ob + (uu + 2*s - 2)] = __float2bfloat16(nxt[uu - S0]);
    float* tswap = cur; cur = nxt; nxt = tswap;
    __syncthreads();
  }
  // ---- B1 chain ----
  cur = bufA; nxt = bufB;
  for (int idx = tid; idx < PBUF; idx += 256){
    int u = S0 + idx; cur[idx] = (u >= 0 && u < SEQ) ? X[u] : 0.f;
  }
  __syncthreads();
  for (int l = 1; l <= 9; l++){
    int w = 1 << l, hw = w >> 1;
    int limit = PBUF - (w - 1);
    for (int idx = tid; idx < limit; idx += 256)
      nxt[idx] = cur[idx] + cur[idx+hw];
    __syncthreads();
    int ust = (q == 0) ? -(w - 1) : q*4096;
    int uen = q*4096 + 4096;
    long ob = offB1(l);
    for (int uu = ust + tid; uu < uen; uu += 256)
      R[ob + (uu + w - 1)] = __float2bfloat16(nxt[uu - S0]);
    float* tswap = cur; cur = nxt; nxt = tswap;
    __syncthreads();
  }
  // ---- local P/Q prefix (fp32) -> M levels ----
  float xr[24]; float ps = 0.f, qs = 0.f;
  for (int e = 0; e < 24; e++){
    int idx = tid*24 + e; int u = S0 + idx;
    float xv = (u >= 0 && u < SEQ) ? X[u] : 0.f;
    xr[e] = xv; ps += xv; qs += (float)u * xv;
  }
  sp[tid] = ps; sq[tid] = qs;
  __syncthreads();
  if (tid == 0){
    float a = 0.f, bq = 0.f;
    for (int k = 0; k < 256; k++){
      float t1 = sp[k]; sp[k] = a;  a  += t1;
      float t2 = sq[k]; sq[k] = bq; bq += t2;
    }
  }
  __syncthreads();
  float rp = sp[tid], rq = sq[tid];
  for (int e = 0; e < 24; e++){
    int idx = tid*24 + e; int u = S0 + idx;
    bufA[idx] = rp; bufB[idx] = rq;
    rp += xr[e]; rq += (float)u * xr[e];
  }
  __syncthreads();
  for (int l = 1; l <= 9; l++){
    int w = 1 << l;
    int ust = (q == 0) ? -(w - 1) : q*4096;
    int uen = q*4096 + 4096;
    long ob = offM(l);
    for (int uu = ust + tid; uu < uen; uu += 256){
      int ilo = uu - S0, ihi = uu + w - S0;
      float val = (bufB[ihi] - bufB[ilo]) - (float)uu * (bufA[ihi] - bufA[ilo]);
      R[ob + (uu + w - 1)] = __float2bfloat16(val);
    }
  }
}

// ---------------- bounded pyramid reads ----------------
__device__ inline float rdl(const __hip_bfloat16* __restrict__ R, long off, int lo, int u){
  if (u < lo || u >= SEQ) return 0.f;
  return __bfloat162float(R[off + (u - lo)]);
}
__device__ inline float rdh(const __hip_bfloat16* __restrict__ R, const float* __restrict__ X,
                            long off, int lo, int l, int u){
  if (l == 1) return (u >= 0 && u < SEQ) ? X[u] : 0.f;  // B1_1 == x
  return rdl(R, off, lo, u);
}

// ---------------- GEMM kernel: 64 t-rows x 32 o per block ----------------
__global__ __launch_bounds__(256) void gemm_k(const float* __restrict__ x,
                                              const uint32_t* __restrict__ wts,
                                              const __hip_bfloat16* __restrict__ lv,
                                              float* __restrict__ out,
                                              int b0, long rowe){
  __shared__ short Ab[2][64*40];
  __shared__ short Wb[2][32*40];
  __shared__ float Ob[64*33];
  int tid = threadIdx.x;
  int bl = blockIdx.x >> 8, tile = blockIdx.x & 255;
  int b = b0 + bl, T0 = tile << 6;
  int wid = tid >> 6, lane = tid & 63;
  f32x4 acc0 = {0.f,0.f,0.f,0.f}, acc1 = {0.f,0.f,0.f,0.f};

  auto stage = [&](int st, int bi){
    SInfo si = decode(st);
    int s = 1 << si.l;
    long oB2 = offB2(si.l), oB1 = offB1(si.l), oM = offM(si.l);
    long oB1h = (si.l > 1) ? offB1(si.l - 1) : 0;
    int loB2 = -(2*s - 2), loB1 = -(s - 1), loB1h = -((s >> 1) - 1);
    float inv2s = 0.5f/(float)s, c2m1 = (float)(2*s - 1);
    int off = 16*(s - 1);
    // weights -> LDS
    for (int r2 = 0; r2 < 2; r2++){
      int f2 = r2*256 + tid;
      int o = f2 >> 4, ii = f2 & 15;
      *(uint32_t*)&Wb[bi][o*40 + ii*2] = wts[(size_t)st*512 + f2];
    }
    // A values -> LDS
    for (int r = 0; r < 8; r++){
      int flat = r*256 + tid;
      int t = flat & 63, i = flat >> 6;
      const __hip_bfloat16* R = lv + (size_t)(bl*32 + i)*rowe;
      const float* X = x + ((size_t)(b*32 + i) << 14);
      int tg = T0 + t;
      float v = 0.f;
      if (si.type == 0){
        v = X[tg];
      } else if (si.type == 1){
        int ix = si.g ? (tg + 1 + si.p) : (tg - 1 - si.p);
        v = (ix >= 0 && ix < SEQ) ? X[ix] : 0.f;
      } else if (si.type == 2){
        int a = si.g ? (tg + 1 + off + si.p*s - (s >> 1))
                     : (tg - 1 - off - si.p*s - 3*(s >> 1) + 1);
        v = rdl(R, oB2, loB2, a) + rdl(R, oB2, loB2, a + 1);
      } else if (si.type == 3){
        if (si.g){ int t0 = tg + 1 + off; int u = t0 - 3*(s >> 1);
          v = (2.f*rdl(R,oM,loB1,u) + rdl(R,oB1,loB1,u))*inv2s
            + rdh(R,X,oB1h,loB1h,si.l, t0 - (s >> 1));
        } else { int Cc = tg - 1 - off; int u = Cc + (s >> 1) + 1;
          v = (c2m1*rdl(R,oB1,loB1,u) - 2.f*rdl(R,oM,loB1,u))*inv2s
            + rdh(R,X,oB1h,loB1h,si.l, Cc + 1);
        }
      } else if (si.type == 4){
        if (si.g){ int t0 = tg + 1 + off; int u = t0 + 16*s + (s >> 1);
          v = (c2m1*rdl(R,oB1,loB1,u) - 2.f*rdl(R,oM,loB1,u))*inv2s
            + rdh(R,X,oB1h,loB1h,si.l, t0 + 16*s);
        } else { int Cc = tg - 1 - off; int u = Cc - 17*s - (s >> 1) + 1;
          v = (2.f*rdl(R,oM,loB1,u) + rdl(R,oB1,loB1,u))*inv2s
            + rdh(R,X,oB1h,loB1h,si.l, Cc - 16*s - (s >> 1) + 1);
        }
      } else { // type 5: l=10 truncated part == 16-box of K0
        long ob16 = offB1(4); int lo16 = -15;
        int u = si.g ? (tg + 16369) : (tg - 16384);
        v = rdl(R, ob16, lo16, u);
      }
      Ab[bi][t*40 + i] = f2b(v);
    }
  };

  stage(0, 0);
  __syncthreads();
  for (int st = 0; st < NSTEP; st++){
    int bi = st & 1;
    if (st + 1 < NSTEP) stage(st + 1, bi ^ 1);
    int trow = (wid << 4) + (lane & 15);
    int kb = (lane >> 4) << 3;
    short8 av  = *(short8*)&Ab[bi][trow*40 + kb];
    short8 bv0 = *(short8*)&Wb[bi][(lane & 15)*40 + kb];
    short8 bv1 = *(short8*)&Wb[bi][((lane & 15) + 16)*40 + kb];
    acc0 = __builtin_amdgcn_mfma_f32_16x16x32_bf16(av, bv0, acc0, 0, 0, 0);
    acc1 = __builtin_amdgcn_mfma_f32_16x16x32_bf16(av, bv1, acc1, 0, 0, 0);
    __syncthreads();
  }
  // epilogue: transpose through LDS for coalesced writes
  {
    int o0 = lane & 15;
    int r0 = (wid << 4) + ((lane >> 4) << 2);
    for (int r = 0; r < 4; r++){
      Ob[(r0 + r)*33 + o0]      = acc0[r];
      Ob[(r0 + r)*33 + o0 + 16] = acc1[r];
    }
    __syncthreads();
    for (int r = 0; r < 8; r++){
      int flat = r*256 + tid;
      int o = flat >> 6, t = flat & 63;
      out[((size_t)(b*32 + o) << 14) + T0 + t] = Ob[t*33 + o];
    }
  }
}

// ---------------- launcher ----------------
extern "C" void kernel_launch(void* const* d_in, const int* in_sizes, int n_in,
                              void* d_out, int out_size, void* d_ws, size_t ws_size,
                              hipStream_t stream) {
  const float* x    = (const float*)d_in[0];
  const float* kern = (const float*)d_in[1];
  const float* cen  = (const float*)d_in[2];
  float* out = (float*)d_out;
  char* ws = (char*)d_ws;

  float* invn = (float*)ws;                                   // 1024 f32
  __hip_bfloat16* wts = (__hip_bfloat16*)(ws + 4096);         // NSTEP*1024 bf16
  size_t o_lv = (4096 + (size_t)NSTEP*1024*2 + 1023) & ~(size_t)1023;
  __hip_bfloat16* lv = (__hip_bfloat16*)(ws + o_lv);

  long rowe = rowElems();
  size_t row_bytes = (size_t)rowe * 2;
  int bc = 1;
  if      (o_lv + (size_t)8*32*row_bytes <= ws_size) bc = 8;
  else if (o_lv + (size_t)4*32*row_bytes <= ws_size) bc = 4;
  else if (o_lv + (size_t)2*32*row_bytes <= ws_size) bc = 2;

  norm_k<<<1024, 256, 0, stream>>>(kern, cen, invn);
  wts_k<<<NSTEP, 256, 0, stream>>>(kern, cen, invn, wts);
  for (int b0 = 0; b0 < 8; b0 += bc){
    pyr_k<<<bc*128, 256, 0, stream>>>(x, lv, b0, rowe);
    gemm_k<<<bc*256, 256, 0, stream>>>(x, (const uint32_t*)wts, lv, out, b0, rowe);
  }
}

// Round 2
// 818.897 us; speedup vs baseline: 4.8974x; 4.8974x over previous
//
#include <hip/hip_runtime.h>
#include <hip/hip_bf16.h>
#include <stdint.h>

#define SEQ    16384
#define NKL    11
#define NSTEP  467
#define TPAD   2048
#define TROWS  (SEQ + 2*TPAD)   // 20480 fp32 temp rows, u in [-2048, 18432)

typedef __attribute__((ext_vector_type(8))) short short8;
typedef __attribute__((ext_vector_type(4))) float f32x4;

// ---- transposed bf16 array table: 0=Xt, 1..9=T_l, 10..18=B1_{2^l}, 19..27=M_{2^l}
__host__ __device__ inline int arrUlo(int a){
  if (a == 0) return 0;
  if (a <= 9) return -(2*(1<<a) - 2);
  int lv = (a <= 18) ? (a-9) : (a-18);
  return -((1<<lv) - 1);
}
__host__ __device__ inline int arrRowsPadded(int a){ return SEQ - arrUlo(a) + 128; }
__host__ __device__ inline long arrOff(int a){ long o=0; for (int k=0;k<a;k++) o += arrRowsPadded(k); return o; }
__host__ __device__ inline long totRowsF(){ return arrOff(28); }

__device__ inline float multf(int l){ return (float)(pow(0.5, (double)l/4096.0)*0.9 + 0.1); }
__device__ inline float Kv(const float* kern, int l, int g, int o, int i, int p){
  return kern[ (((size_t)((l*2 + g)*32 + o))*32 + i)*16 + p ];
}

struct Step { int arr; int c; int l; int g; int kidx; float coeff; };

__device__ inline Step decode(int st){
  Step r;
  if (st == 0){ r = {0, 0, 0, 0, 0, 1.f}; return r; }
  if (st < 17){ int p = st-1;  r = {0, 1+p,  0, 1, p, 1.f}; return r; }
  if (st < 33){ int p = st-17; r = {0, -1-p, 0, 0, p, 1.f}; return r; }
  if (st < 465){
    int t = st-33; int blk = t/24, k = t%24;
    int l = 1 + blk/2; int g = (blk & 1) ? 0 : 1;
    int s = 1<<l, hs = s>>1, off = 16*(s-1);
    float inv2s = 0.5f/(float)s;
    int arrT = l, arrB1 = 9+l, arrM = 18+l, arrH = (l==1) ? 0 : (8+l);
    if (k < 18){
      int p = k-1; int pp = p < 0 ? 0 : (p > 15 ? 15 : p);
      int c = g ? (1+off+p*s-hs) : (-off-p*s-3*hs);
      r = {arrT, c, l, g, pp, inv2s}; return r;
    }
    int kk = k-18;
    if (g){
      int c3 = 1+off-3*hs, c3h = 1+off-hs, c4 = 1+off+16*s+hs, c4h = 1+off+16*s;
      switch(kk){
        case 0: r = {arrM,  c3,  l, g, 0,  -2.f*inv2s}; return r;
        case 1: r = {arrB1, c3,  l, g, 0,  -inv2s}; return r;
        case 2: r = {arrH,  c3h, l, g, 0,  -1.f}; return r;
        case 3: r = {arrB1, c4,  l, g, 15, -(2.f*s-1.f)*inv2s}; return r;
        case 4: r = {arrM,  c4,  l, g, 15, +2.f*inv2s}; return r;
        default:r = {arrH,  c4h, l, g, 15, -1.f}; return r;
      }
    } else {
      int c3 = -off+hs, c3h = -off, c4 = -off-17*s-hs, c4h = -off-16*s-hs;
      switch(kk){
        case 0: r = {arrB1, c3,  l, g, 0,  -(2.f*s-1.f)*inv2s}; return r;
        case 1: r = {arrM,  c3,  l, g, 0,  +2.f*inv2s}; return r;
        case 2: r = {arrH,  c3h, l, g, 0,  -1.f}; return r;
        case 3: r = {arrM,  c4,  l, g, 15, -2.f*inv2s}; return r;
        case 4: r = {arrB1, c4,  l, g, 15, -inv2s}; return r;
        default:r = {arrH,  c4h, l, g, 15, -1.f}; return r;
      }
    }
  }
  if (st == 465){ r = {13, 16369, 10, 1, 0, 1.f}; return r; }
  r = {13, -16384, 10, 0, 0, 1.f}; return r;
}

// ---------------- norm kernel (unchanged, verified) ----------------
__global__ __launch_bounds__(256) void norm_k(const float* __restrict__ kern,
                                              const float* __restrict__ cen,
                                              float* __restrict__ invn){
  int o = blockIdx.x >> 5, i = blockIdx.x & 31, tid = threadIdx.x;
  float mlt[NKL];
  for (int l = 0; l < NKL; l++) mlt[l] = multf(l);
  double acc = 0.0;
  for (int pos = tid; pos < 2*SEQ; pos += 256){
    int r = pos & (SEQ-1);
    int lr = (r >> 4) + 1;
    int l  = 31 - __clz(lr);
    int s  = 1 << l;
    int j  = r - 16*(s - 1);
    float c = (j + 0.5f)/(float)s - 0.5f;
    c = fminf(fmaxf(c, 0.f), 15.f);
    int i0 = (int)floorf(c);
    int i1 = (i0+1 < 15) ? i0+1 : 15;
    float w = c - (float)i0;
    int g = pos >> 14;
    float v = Kv(kern,l,g,o,i,i0)*(1.f-w) + Kv(kern,l,g,o,i,i1)*w;
    v *= mlt[l];
    acc += (double)v * v;
  }
  __shared__ double sred[256];
  sred[tid] = acc; __syncthreads();
  for (int ofs = 128; ofs > 0; ofs >>= 1){ if (tid < ofs) sred[tid] += sred[tid+ofs]; __syncthreads(); }
  if (tid == 0){
    float cc = cen[o*32 + i];
    double tot = sred[0] + (double)cc*cc;
    invn[o*32 + i] = (float)(1.0 / sqrt(tot));
  }
}

// ---------------- weights: W[step][o][i] bf16, coeff folded in ----------------
__global__ __launch_bounds__(256) void wts_k(const float* __restrict__ kern,
                                             const float* __restrict__ cen,
                                             const float* __restrict__ invn,
                                             __hip_bfloat16* __restrict__ wts){
  int st = blockIdx.x;
  Step sp = decode(st);
  float m = multf(sp.l);
  for (int idx = threadIdx.x; idx < 1024; idx += 256){
    int o = idx >> 5, i = idx & 31;
    float in = invn[o*32 + i];
    float w;
    if (st == 0) w = cen[o*32 + i] * in;
    else         w = m * Kv(kern, sp.l, sp.g, o, i, sp.kidx) * in * sp.coeff;
    wts[(size_t)st*1024 + idx] = __float2bfloat16(w);
  }
}

// ---------------- step table ----------------
__global__ void setup_k(int4* __restrict__ stab){
  int st = blockIdx.x*256 + threadIdx.x;
  if (st >= NSTEP) return;
  Step sp = decode(st);
  int ulo = arrUlo(sp.arr);
  long base = arrOff(sp.arr) + (sp.c - ulo) + 64;
  int t0lo = ulo - 63 - sp.c;
  int t0hi = SEQ - 1 - sp.c;
  stab[st] = make_int4((int)base, t0lo, t0hi, 0);
}

// ---------------- x transpose: [b][i][u] fp32 -> xt32 [u][i] fp32 + Xt bf16 ----------------
__global__ __launch_bounds__(256) void xtr_k(const float* __restrict__ x,
                                             float* __restrict__ xt32,
                                             __hip_bfloat16* __restrict__ tr, int b0){
  long tR = totRowsF();
  int bl = blockIdx.x / 320, ut = blockIdx.x % 320;
  int b = b0 + bl;
  __shared__ float tile[32][65];
  int tid = threadIdx.x;
  int i = tid >> 3, seg = tid & 7;
  int u0 = ut*64 - TPAD;
  bool inr = (u0 >= 0) && (u0 + 64 <= SEQ);
  float v[8];
  if (inr){
    const float* xp = x + (((size_t)(b*32 + i)) << 14) + u0 + seg*8;
    *(f32x4*)&v[0] = *(const f32x4*)xp;
    *(f32x4*)&v[4] = *(const f32x4*)(xp + 4);
  } else {
    for (int e = 0; e < 8; e++) v[e] = 0.f;
  }
  for (int e = 0; e < 8; e++) tile[i][seg*8 + e] = v[e];
  __syncthreads();
  int ul = tid >> 2, ib = (tid & 3) << 3;
  float o[8];
  for (int e = 0; e < 8; e++) o[e] = tile[ib + e][ul];
  int row = ut*64 + ul;
  float* q = xt32 + ((size_t)bl*TROWS + row)*32 + ib;
  *(f32x4*)q       = *(f32x4*)&o[0];
  *(f32x4*)(q + 4) = *(f32x4*)&o[4];
  int u = u0 + ul;
  int pr = u + 64;                       // arr0: ulo=0, pad 64
  if (pr >= 0 && pr < SEQ + 128){
    union { ushort us[8]; short8 s8; } pk;
    for (int e = 0; e < 8; e++){
      __hip_bfloat16 h = __float2bfloat16(o[e]);
      pk.us[e] = __builtin_bit_cast(ushort, h);
    }
    *(short8*)(tr + ((size_t)bl*tR + pr)*32 + ib) = pk.s8;
  }
}

// ---------------- doubling pass: level l produces width 2^l from 2^(l-1) ----------------
__device__ inline f32x4 ld4(const float* p, int row, int ib){
  if ((unsigned)row < (unsigned)TROWS) return *(const f32x4*)(p + (size_t)row*32 + ib);
  f32x4 z = {0.f,0.f,0.f,0.f}; return z;
}
__device__ inline void st4b(__hip_bfloat16* p, f32x4 v){
  union { ushort u[4]; uint2 q; } t;
  t.u[0] = __builtin_bit_cast(ushort, __float2bfloat16(v.x));
  t.u[1] = __builtin_bit_cast(ushort, __float2bfloat16(v.y));
  t.u[2] = __builtin_bit_cast(ushort, __float2bfloat16(v.z));
  t.u[3] = __builtin_bit_cast(ushort, __float2bfloat16(v.w));
  *(uint2*)p = t.q;
}

__global__ __launch_bounds__(256) void lvl_k(const float* __restrict__ inB2,
                                             const float* __restrict__ inB1,
                                             const float* __restrict__ inM,
                                             float* __restrict__ outB2,
                                             float* __restrict__ outB1,
                                             float* __restrict__ outM,
                                             __hip_bfloat16* __restrict__ tr,
                                             int l, int CH){
  long tR = totRowsF();
  int s = 1 << (l-1);
  int aT = l, aB = 9+l, aM = 18+l;
  int uloT = arrUlo(aT), uloB = arrUlo(aB);
  long offT = arrOff(aT), offB = arrOff(aB), offM2 = arrOff(aM);
  int rT = arrRowsPadded(aT), rB = arrRowsPadded(aB);
  long totalF4 = (long)CH * TROWS * 8;
  for (long t = (long)blockIdx.x*256 + threadIdx.x; t < totalF4; t += (long)gridDim.x*256){
    int bl = (int)(t / (TROWS*8));
    long rem = t - (long)bl*(TROWS*8);
    int r = (int)(rem >> 3), ib = ((int)rem & 7) << 2;
    const float* pB2 = inB2 + (size_t)bl*TROWS*32;
    const float* pB1 = inB1 + (size_t)bl*TROWS*32;
    const float* pM  = inM  + (size_t)bl*TROWS*32;
    f32x4 a0  = ld4(pB2, r,       ib), a1  = ld4(pB2, r+1,     ib);
    f32x4 as  = ld4(pB2, r+s,     ib), as1 = ld4(pB2, r+s+1,   ib);
    f32x4 a2  = ld4(pB2, r+2*s,   ib), a21 = ld4(pB2, r+2*s+1, ib);
    f32x4 o2 = a0 + 2.f*as + a2;
    f32x4 tt = o2 + a1 + 2.f*as1 + a21;
    f32x4 b0 = ld4(pB1, r, ib), bw = ld4(pB1, r+s, ib);
    f32x4 bo = b0 + bw;
    f32x4 mo;
    if (l == 1) mo = as;                       // M_2[u] = x[u+1]
    else { f32x4 m0 = ld4(pM, r, ib), mw = ld4(pM, r+s, ib); mo = m0 + mw + (float)s*bw; }
    size_t ob = (size_t)bl*TROWS*32 + (size_t)r*32 + ib;
    *(f32x4*)(outB2 + ob) = o2;
    *(f32x4*)(outB1 + ob) = bo;
    *(f32x4*)(outM  + ob) = mo;
    int u = r - TPAD;
    __hip_bfloat16* trb = tr + (size_t)bl*tR*32;
    int pT = u - (uloT - 64);
    if ((unsigned)pT < (unsigned)rT) st4b(trb + ((size_t)(offT + pT))*32 + ib, tt);
    int pB = u - (uloB - 64);
    if ((unsigned)pB < (unsigned)rB){
      st4b(trb + ((size_t)(offB  + pB))*32 + ib, bo);
      st4b(trb + ((size_t)(offM2 + pB))*32 + ib, mo);
    }
  }
}

// ---------------- GEMM: window-load + MFMA, 2-phase pipeline ----------------
__device__ inline void gload16(const void* g, void* l){
  __builtin_amdgcn_global_load_lds(
      (const __attribute__((address_space(1))) void*)g,
      (__attribute__((address_space(3))) void*)l, 16, 0, 0);
}

__global__ __launch_bounds__(256) void gemm2_k(const __hip_bfloat16* __restrict__ tr,
                                               const __hip_bfloat16* __restrict__ wts,
                                               const int4* __restrict__ stab,
                                               float* __restrict__ out, int b0){
  __shared__ __align__(16) short Ab[2][2048];
  __shared__ __align__(16) short Wb[2][1024];
  __shared__ float Ob[64*33];
  long tR = totRowsF();
  int tid = threadIdx.x, wid = tid >> 6, lane = tid & 63;
  int bl = blockIdx.x >> 8, tile = blockIdx.x & 255, T0 = tile << 6;
  int b = b0 + bl;
  const short* trb = (const short*)tr + (size_t)bl*tR*32;
  const short* wp = (const short*)wts;
  long maxRow = tR - 64;
  f32x4 acc0 = {0.f,0.f,0.f,0.f}, acc1 = {0.f,0.f,0.f,0.f};

  auto stage = [&](int st, const int4& e, int buf){
    long r0 = (long)e.x + T0;
    if (r0 < 0) r0 = 0;
    if (r0 > maxRow) r0 = maxRow;
    const short* g = trb + r0*32;
    gload16(g + tid*8, &Ab[buf][wid << 9]);
    if (wid < 2) gload16(wp + (size_t)st*1024 + tid*8, &Wb[buf][wid << 9]);
  };

  int4 e = stab[0];
  bool act = (T0 >= e.y) && (T0 <= e.z);
  if (act) stage(0, e, 0);
  asm volatile("s_waitcnt vmcnt(0)" ::: "memory");
  __builtin_amdgcn_s_barrier();

  for (int st = 0; st < NSTEP; ++st){
    int bi = st & 1;
    int4 en; bool actn = false;
    if (st + 1 < NSTEP){
      en = stab[st + 1];
      actn = (T0 >= en.y) && (T0 <= en.z);
      if (actn) stage(st + 1, en, bi ^ 1);
    }
    if (act){
      int trow = (wid << 4) + (lane & 15);
      int kb = (lane >> 4) << 3;
      short8 av  = *(const short8*)&Ab[bi][trow*32 + kb];
      short8 bv0 = *(const short8*)&Wb[bi][(lane & 15)*32 + kb];
      short8 bv1 = *(const short8*)&Wb[bi][((lane & 15) + 16)*32 + kb];
      acc0 = __builtin_amdgcn_mfma_f32_16x16x32_bf16(av, bv0, acc0, 0, 0, 0);
      acc1 = __builtin_amdgcn_mfma_f32_16x16x32_bf16(av, bv1, acc1, 0, 0, 0);
    }
    asm volatile("s_waitcnt vmcnt(0) lgkmcnt(0)" ::: "memory");
    __builtin_amdgcn_s_barrier();
    e = en; act = actn;
  }

  // epilogue: transpose through LDS for coalesced writes
  {
    int o0 = lane & 15;
    int r0 = (wid << 4) + ((lane >> 4) << 2);
    for (int r2 = 0; r2 < 4; ++r2){
      Ob[(r0 + r2)*33 + o0]      = acc0[r2];
      Ob[(r0 + r2)*33 + o0 + 16] = acc1[r2];
    }
    __syncthreads();
    for (int r2 = 0; r2 < 8; ++r2){
      int flat = r2*256 + tid;
      int o = flat >> 6, t2 = flat & 63;
      out[((size_t)(b*32 + o) << 14) + T0 + t2] = Ob[t2*33 + o];
    }
  }
}

// ---------------- launcher ----------------
extern "C" void kernel_launch(void* const* d_in, const int* in_sizes, int n_in,
                              void* d_out, int out_size, void* d_ws, size_t ws_size,
                              hipStream_t stream) {
  const float* x    = (const float*)d_in[0];
  const float* kern = (const float*)d_in[1];
  const float* cen  = (const float*)d_in[2];
  float* out = (float*)d_out;
  char* ws = (char*)d_ws;

  long tR = totRowsF();
  size_t oWts  = 4096;
  size_t oStab = oWts + (size_t)NSTEP*1024*2;
  oStab = (oStab + 255) & ~(size_t)255;
  size_t oTr = oStab + (size_t)NSTEP*16;
  oTr = (oTr + 1023) & ~(size_t)1023;

  size_t trB_per  = (size_t)tR * 64;       // bf16 arrays per b
  size_t f32B_per = (size_t)TROWS * 128;   // one fp32 buffer per b
  int CH = 1;
  int cands[4] = {8,4,2,1};
  for (int ci = 0; ci < 4; ci++){
    int c = cands[ci];
    size_t need = oTr + (size_t)c*trB_per + 7*(size_t)c*f32B_per;
    if (need <= ws_size){ CH = c; break; }
  }
  size_t oF32 = oTr + (size_t)CH*trB_per;

  float* invn = (float*)ws;
  __hip_bfloat16* wts = (__hip_bfloat16*)(ws + oWts);
  int4* stab = (int4*)(ws + oStab);
  __hip_bfloat16* tr = (__hip_bfloat16*)(ws + oTr);
  float* fb[7];
  for (int k = 0; k < 7; k++) fb[k] = (float*)(ws + oF32 + (size_t)k*CH*f32B_per);
  float* xt32   = fb[0];
  float* b2b[2] = {fb[1], fb[2]};
  float* b1b[2] = {fb[3], fb[4]};
  float* mb[2]  = {fb[5], fb[6]};

  norm_k<<<1024, 256, 0, stream>>>(kern, cen, invn);
  wts_k<<<NSTEP, 256, 0, stream>>>(kern, cen, invn, wts);
  setup_k<<<2, 256, 0, stream>>>(stab);

  for (int b0 = 0; b0 < 8; b0 += CH){
    xtr_k<<<CH*320, 256, 0, stream>>>(x, xt32, tr, b0);
    for (int l = 1; l <= 9; l++){
      const float* iB2 = (l == 1) ? xt32 : b2b[(l-1) & 1];
      const float* iB1 = (l == 1) ? xt32 : b1b[(l-1) & 1];
      const float* iM  = (l == 1) ? xt32 : mb[(l-1) & 1];
      lvl_k<<<2048, 256, 0, stream>>>(iB2, iB1, iM,
                                      b2b[l & 1], b1b[l & 1], mb[l & 1],
                                      tr, l, CH);
    }
    gemm2_k<<<CH*256, 256, 0, stream>>>(tr, wts, stab, out, b0);
  }
}